// Round 2
// baseline (1698.231 us; speedup 1.0000x reference)
//
#include <hip/hip_runtime.h>
#include <hip/hip_bf16.h>
#include <math.h>

#define BB 8
#define SS 2048
#define HH 8
#define DKK 64
#define DM 512
#define TS 68  // LDS row stride in floats: 272 B = 17*16 (float4-aligned, breaks pow2 bank stride)

__device__ __forceinline__ float bf2f(unsigned short u) {
    return __uint_as_float(((unsigned int)u) << 16);
}
__device__ __forceinline__ unsigned short f2bf(float f) {
    __hip_bfloat16 h = __float2bfloat16(f);
    return *reinterpret_cast<unsigned short*>(&h);
}

// ---------------------------------------------------------------------------
// Runtime input-dtype detection. Genuine bf16 weights (uniform(-1/sqrt(512),
// 1/sqrt(512))) satisfy |w| <= 0.0442 < 0.05 for every ushort. If the buffer
// actually holds fp32, the low-half ushorts have random exponent fields ->
// ~50% trip |x|>=0.05 (or NaN). flag=1 -> bf16 storage, flag=0 -> fp32.
// ---------------------------------------------------------------------------
__global__ void detect_dtype_kernel(const unsigned short* __restrict__ w,
                                    int* __restrict__ flag) {
    __shared__ int cnt;
    if (threadIdx.x == 0) cnt = 0;
    __syncthreads();
    int c = 0;
    for (int i = threadIdx.x; i < 2048; i += 256) {
        float f = bf2f(w[i]);
        if (!(fabsf(f) < 0.05f)) c++;   // also trips on NaN
    }
    if (c) atomicAdd(&cnt, c);
    __syncthreads();
    if (threadIdx.x == 0) *flag = (cnt == 0) ? 1 : 0;
}

// ---------------------------------------------------------------------------
// Projection GEMM: out[m][n] = sum_k X[m][k]*W[n][k] + bias[n]
// X [16384,512], W [512,512] row-major [n][k]; dtype per flag.
// out bf16 scattered to [B,H,S,64] (n = h*64+d).
// BM=64, BN=64, BK=16, 256 threads, 4x4 micro-tile, fp32 accumulate.
// ---------------------------------------------------------------------------
__global__ __launch_bounds__(256) void proj_qkv_kernel(
    const void* __restrict__ X,
    const void* __restrict__ W,
    const void* __restrict__ bias,
    unsigned short* __restrict__ out,
    const int* __restrict__ flagp)
{
    __shared__ __align__(16) float As[16][TS];  // As[k][m]
    __shared__ __align__(16) float Bs[16][TS];  // Bs[k][n]
    const int isbf = *flagp;
    const int t = threadIdx.x;
    const int tx = t & 15, ty = t >> 4;
    const int m0 = blockIdx.y * 64, n0 = blockIdx.x * 64;
    const int lm = t >> 2, lk = (t & 3) * 4;
    float acc[4][4] = {};

    const size_t xoff = (size_t)(m0 + lm) * DM + lk;
    const size_t woff = (size_t)(n0 + lm) * DM + lk;

    for (int k0 = 0; k0 < DM; k0 += 16) {
        float xv0, xv1, xv2, xv3, wv0, wv1, wv2, wv3;
        if (isbf) {
            ushort4 xa = *(const ushort4*)((const unsigned short*)X + xoff + k0);
            ushort4 wb = *(const ushort4*)((const unsigned short*)W + woff + k0);
            xv0 = bf2f(xa.x); xv1 = bf2f(xa.y); xv2 = bf2f(xa.z); xv3 = bf2f(xa.w);
            wv0 = bf2f(wb.x); wv1 = bf2f(wb.y); wv2 = bf2f(wb.z); wv3 = bf2f(wb.w);
        } else {
            float4 xa = *(const float4*)((const float*)X + xoff + k0);
            float4 wb = *(const float4*)((const float*)W + woff + k0);
            xv0 = xa.x; xv1 = xa.y; xv2 = xa.z; xv3 = xa.w;
            wv0 = wb.x; wv1 = wb.y; wv2 = wb.z; wv3 = wb.w;
        }
        __syncthreads();
        As[lk + 0][lm] = xv0; As[lk + 1][lm] = xv1;
        As[lk + 2][lm] = xv2; As[lk + 3][lm] = xv3;
        Bs[lk + 0][lm] = wv0; Bs[lk + 1][lm] = wv1;
        Bs[lk + 2][lm] = wv2; Bs[lk + 3][lm] = wv3;
        __syncthreads();
#pragma unroll
        for (int kk = 0; kk < 16; kk++) {
            float4 a = *(const float4*)&As[kk][ty * 4];
            float4 b = *(const float4*)&Bs[kk][tx * 4];
            acc[0][0] += a.x * b.x; acc[0][1] += a.x * b.y; acc[0][2] += a.x * b.z; acc[0][3] += a.x * b.w;
            acc[1][0] += a.y * b.x; acc[1][1] += a.y * b.y; acc[1][2] += a.y * b.z; acc[1][3] += a.y * b.w;
            acc[2][0] += a.z * b.x; acc[2][1] += a.z * b.y; acc[2][2] += a.z * b.z; acc[2][3] += a.z * b.w;
            acc[3][0] += a.w * b.x; acc[3][1] += a.w * b.y; acc[3][2] += a.w * b.z; acc[3][3] += a.w * b.w;
        }
    }
    float b0, b1, b2, b3;
    if (isbf) {
        ushort4 bb4 = *(const ushort4*)((const unsigned short*)bias + n0 + tx * 4);
        b0 = bf2f(bb4.x); b1 = bf2f(bb4.y); b2 = bf2f(bb4.z); b3 = bf2f(bb4.w);
    } else {
        float4 bb4 = *(const float4*)((const float*)bias + n0 + tx * 4);
        b0 = bb4.x; b1 = bb4.y; b2 = bb4.z; b3 = bb4.w;
    }
    const int h = n0 >> 6;
#pragma unroll
    for (int i = 0; i < 4; i++) {
        int m = m0 + ty * 4 + i;
        int bb = m >> 11;           // m / S
        int srow = m & (SS - 1);    // m % S
        ushort4 r;
        r.x = f2bf(acc[i][0] + b0);
        r.y = f2bf(acc[i][1] + b1);
        r.z = f2bf(acc[i][2] + b2);
        r.w = f2bf(acc[i][3] + b3);
        *(ushort4*)(out + ((((size_t)bb * HH + h) * SS + srow) << 6) + tx * 4) = r;
    }
}

// ---------------------------------------------------------------------------
// Flash attention (fp32 compute, bf16 q/k/v in ws): one block = one (b,h) x
// 64 q rows; loop kv in tiles of 64. Exact reference mask semantics.
// ---------------------------------------------------------------------------
__global__ __launch_bounds__(256) void attn_kernel(
    const unsigned short* __restrict__ qf, const unsigned short* __restrict__ kf,
    const unsigned short* __restrict__ vf, const int* __restrict__ mask,
    unsigned short* __restrict__ ao)   // [B,S,H,64] bf16
{
    __shared__ __align__(16) float Qt[DKK][TS]; // Qt[d][qi], pre-scaled by 1/8
    __shared__ __align__(16) float Kt[DKK][TS]; // Kt[d][ki]
    __shared__ __align__(16) float Vt[64][TS];  // Vt[ki][d]
    __shared__ __align__(16) float Ps[64][TS];  // Ps[ki][qi]
    const int t = threadIdx.x, tx = t & 15, ty = t >> 4;
    const int q0 = blockIdx.x * 64;
    const int bh = blockIdx.y;   // b*8 + h
    const unsigned short* qb = qf + (size_t)bh * SS * DKK;
    const unsigned short* kb = kf + (size_t)bh * SS * DKK;
    const unsigned short* vb = vf + (size_t)bh * SS * DKK;

#pragma unroll
    for (int rep = 0; rep < 4; rep++) {
        int idx = rep * 1024 + t * 4;
        int row = idx >> 6, dd = idx & 63;
        ushort4 v = *(const ushort4*)(qb + (size_t)(q0 + row) * DKK + dd);
        Qt[dd + 0][row] = bf2f(v.x) * 0.125f;
        Qt[dd + 1][row] = bf2f(v.y) * 0.125f;
        Qt[dd + 2][row] = bf2f(v.z) * 0.125f;
        Qt[dd + 3][row] = bf2f(v.w) * 0.125f;
    }
    float m_i[4], l_i[4], O[4][4] = {};
#pragma unroll
    for (int i = 0; i < 4; i++) { m_i[i] = -INFINITY; l_i[i] = 0.f; }

    for (int kv0 = 0; kv0 < SS; kv0 += 64) {
        __syncthreads();   // previous PV (reads Ps/Vt) done before restage
#pragma unroll
        for (int rep = 0; rep < 4; rep++) {
            int idx = rep * 1024 + t * 4;
            int row = idx >> 6, dd = idx & 63;
            ushort4 kv = *(const ushort4*)(kb + (size_t)(kv0 + row) * DKK + dd);
            Kt[dd + 0][row] = bf2f(kv.x); Kt[dd + 1][row] = bf2f(kv.y);
            Kt[dd + 2][row] = bf2f(kv.z); Kt[dd + 3][row] = bf2f(kv.w);
            ushort4 vv = *(const ushort4*)(vb + (size_t)(kv0 + row) * DKK + dd);
            Vt[row][dd + 0] = bf2f(vv.x); Vt[row][dd + 1] = bf2f(vv.y);
            Vt[row][dd + 2] = bf2f(vv.z); Vt[row][dd + 3] = bf2f(vv.w);
        }
        __syncthreads();

        float s[4][4] = {};
#pragma unroll 8
        for (int d = 0; d < DKK; d++) {
            float4 a = *(const float4*)&Qt[d][ty * 4];
            float4 b = *(const float4*)&Kt[d][tx * 4];
            s[0][0] += a.x * b.x; s[0][1] += a.x * b.y; s[0][2] += a.x * b.z; s[0][3] += a.x * b.w;
            s[1][0] += a.y * b.x; s[1][1] += a.y * b.y; s[1][2] += a.y * b.z; s[1][3] += a.y * b.w;
            s[2][0] += a.z * b.x; s[2][1] += a.z * b.y; s[2][2] += a.z * b.z; s[2][3] += a.z * b.w;
            s[3][0] += a.w * b.x; s[3][1] += a.w * b.y; s[3][2] += a.w * b.z; s[3][3] += a.w * b.w;
        }
#pragma unroll
        for (int i = 0; i < 4; i++) {
            int4 mk = *(const int4*)(mask + (size_t)(q0 + ty * 4 + i) * SS + kv0 + tx * 4);
            if (mk.x == 0) s[i][0] = -1e30f;
            if (mk.y == 0) s[i][1] = -1e30f;
            if (mk.z == 0) s[i][2] = -1e30f;
            if (mk.w == 0) s[i][3] = -1e30f;
        }
#pragma unroll
        for (int i = 0; i < 4; i++) {
            float mt = fmaxf(fmaxf(s[i][0], s[i][1]), fmaxf(s[i][2], s[i][3]));
            mt = fmaxf(mt, __shfl_xor(mt, 1));
            mt = fmaxf(mt, __shfl_xor(mt, 2));
            mt = fmaxf(mt, __shfl_xor(mt, 4));
            mt = fmaxf(mt, __shfl_xor(mt, 8));
            float mnew = fmaxf(m_i[i], mt);
            float alpha = __expf(m_i[i] - mnew);   // first iter: exp(-inf)=0
            m_i[i] = mnew;
            float rs = 0.f;
#pragma unroll
            for (int j = 0; j < 4; j++) {
                float p = __expf(s[i][j] - mnew);
                s[i][j] = p; rs += p;
            }
            rs += __shfl_xor(rs, 1); rs += __shfl_xor(rs, 2);
            rs += __shfl_xor(rs, 4); rs += __shfl_xor(rs, 8);
            l_i[i] = l_i[i] * alpha + rs;
#pragma unroll
            for (int j = 0; j < 4; j++) O[i][j] *= alpha;
        }
        // P -> LDS transposed for the PV GEMM
#pragma unroll
        for (int j = 0; j < 4; j++) {
            Ps[tx * 4 + j][ty * 4 + 0] = s[0][j];
            Ps[tx * 4 + j][ty * 4 + 1] = s[1][j];
            Ps[tx * 4 + j][ty * 4 + 2] = s[2][j];
            Ps[tx * 4 + j][ty * 4 + 3] = s[3][j];
        }
        __syncthreads();
#pragma unroll 8
        for (int ki = 0; ki < 64; ki++) {
            float4 a = *(const float4*)&Ps[ki][ty * 4];
            float4 b = *(const float4*)&Vt[ki][tx * 4];
            O[0][0] += a.x * b.x; O[0][1] += a.x * b.y; O[0][2] += a.x * b.z; O[0][3] += a.x * b.w;
            O[1][0] += a.y * b.x; O[1][1] += a.y * b.y; O[1][2] += a.y * b.z; O[1][3] += a.y * b.w;
            O[2][0] += a.z * b.x; O[2][1] += a.z * b.y; O[2][2] += a.z * b.z; O[2][3] += a.z * b.w;
            O[3][0] += a.w * b.x; O[3][1] += a.w * b.y; O[3][2] += a.w * b.z; O[3][3] += a.w * b.w;
        }
    }
    const int bb = bh >> 3, h = bh & 7;
#pragma unroll
    for (int i = 0; i < 4; i++) {
        float inv = 1.f / l_i[i];
        int q = q0 + ty * 4 + i;
        ushort4 r;
        r.x = f2bf(O[i][0] * inv); r.y = f2bf(O[i][1] * inv);
        r.z = f2bf(O[i][2] * inv); r.w = f2bf(O[i][3] * inv);
        *(ushort4*)(ao + ((((size_t)bb * SS + q) * HH + h) << 6) + tx * 4) = r;
    }
}

// ---------------------------------------------------------------------------
// Final projection: out[m][n] = sum_k A[m][k]*Wo[n][k] + bo[n]
// A bf16 (ws), Wo/bo per flag, out dtype per flag.
// ---------------------------------------------------------------------------
__global__ __launch_bounds__(256) void final_proj_kernel(
    const unsigned short* __restrict__ X,
    const void* __restrict__ W,
    const void* __restrict__ bias,
    void* __restrict__ out,
    const int* __restrict__ flagp)
{
    __shared__ __align__(16) float As[16][TS];
    __shared__ __align__(16) float Bs[16][TS];
    const int isbf = *flagp;
    const int t = threadIdx.x;
    const int tx = t & 15, ty = t >> 4;
    const int m0 = blockIdx.y * 64, n0 = blockIdx.x * 64;
    const int lm = t >> 2, lk = (t & 3) * 4;
    float acc[4][4] = {};

    const size_t xoff = (size_t)(m0 + lm) * DM + lk;
    const size_t woff = (size_t)(n0 + lm) * DM + lk;

    for (int k0 = 0; k0 < DM; k0 += 16) {
        ushort4 xa = *(const ushort4*)(X + xoff + k0);
        float wv0, wv1, wv2, wv3;
        if (isbf) {
            ushort4 wb = *(const ushort4*)((const unsigned short*)W + woff + k0);
            wv0 = bf2f(wb.x); wv1 = bf2f(wb.y); wv2 = bf2f(wb.z); wv3 = bf2f(wb.w);
        } else {
            float4 wb = *(const float4*)((const float*)W + woff + k0);
            wv0 = wb.x; wv1 = wb.y; wv2 = wb.z; wv3 = wb.w;
        }
        __syncthreads();
        As[lk + 0][lm] = bf2f(xa.x);
        As[lk + 1][lm] = bf2f(xa.y);
        As[lk + 2][lm] = bf2f(xa.z);
        As[lk + 3][lm] = bf2f(xa.w);
        Bs[lk + 0][lm] = wv0; Bs[lk + 1][lm] = wv1;
        Bs[lk + 2][lm] = wv2; Bs[lk + 3][lm] = wv3;
        __syncthreads();
#pragma unroll
        for (int kk = 0; kk < 16; kk++) {
            float4 a = *(const float4*)&As[kk][ty * 4];
            float4 b = *(const float4*)&Bs[kk][tx * 4];
            acc[0][0] += a.x * b.x; acc[0][1] += a.x * b.y; acc[0][2] += a.x * b.z; acc[0][3] += a.x * b.w;
            acc[1][0] += a.y * b.x; acc[1][1] += a.y * b.y; acc[1][2] += a.y * b.z; acc[1][3] += a.y * b.w;
            acc[2][0] += a.z * b.x; acc[2][1] += a.z * b.y; acc[2][2] += a.z * b.z; acc[2][3] += a.z * b.w;
            acc[3][0] += a.w * b.x; acc[3][1] += a.w * b.y; acc[3][2] += a.w * b.z; acc[3][3] += a.w * b.w;
        }
    }
    float b0, b1, b2, b3;
    if (isbf) {
        ushort4 bb4 = *(const ushort4*)((const unsigned short*)bias + n0 + tx * 4);
        b0 = bf2f(bb4.x); b1 = bf2f(bb4.y); b2 = bf2f(bb4.z); b3 = bf2f(bb4.w);
    } else {
        float4 bb4 = *(const float4*)((const float*)bias + n0 + tx * 4);
        b0 = bb4.x; b1 = bb4.y; b2 = bb4.z; b3 = bb4.w;
    }
#pragma unroll
    for (int i = 0; i < 4; i++) {
        int m = m0 + ty * 4 + i;
        if (isbf) {
            ushort4 r;
            r.x = f2bf(acc[i][0] + b0);
            r.y = f2bf(acc[i][1] + b1);
            r.z = f2bf(acc[i][2] + b2);
            r.w = f2bf(acc[i][3] + b3);
            *(ushort4*)((unsigned short*)out + (size_t)m * DM + n0 + tx * 4) = r;
        } else {
            float4 r;
            r.x = acc[i][0] + b0; r.y = acc[i][1] + b1;
            r.z = acc[i][2] + b2; r.w = acc[i][3] + b3;
            *(float4*)((float*)out + (size_t)m * DM + n0 + tx * 4) = r;
        }
    }
}

extern "C" void kernel_launch(void* const* d_in, const int* in_sizes, int n_in,
                              void* d_out, int out_size, void* d_ws, size_t ws_size,
                              hipStream_t stream) {
    const void* Q    = d_in[0];
    const void* K    = d_in[1];
    const void* V    = d_in[2];
    const int*  mask = (const int*)d_in[3];
    const void* Wq   = d_in[4];
    const void* bq   = d_in[5];
    const void* Wk   = d_in[6];
    const void* bk   = d_in[7];
    const void* Wv   = d_in[8];
    const void* bv   = d_in[9];
    const void* Wo   = d_in[10];
    const void* bo   = d_in[11];

    // ws layout: [flag int @0, pad to 256] [qb16][kb16][vb16][ab16], 64 MiB + 256 B
    int* flag = (int*)d_ws;
    const size_t SEG = (size_t)BB * HH * SS * DKK;  // 8,388,608 elements
    unsigned short* qb = (unsigned short*)((char*)d_ws + 256);
    unsigned short* kb = qb + SEG;
    unsigned short* vb = kb + SEG;
    unsigned short* ab = vb + SEG;

    detect_dtype_kernel<<<1, 256, 0, stream>>>((const unsigned short*)Wq, flag);

    dim3 gg(DM / 64, (BB * SS) / 64);  // (8, 256)
    proj_qkv_kernel<<<gg, 256, 0, stream>>>(Q, Wq, bq, qb, flag);
    proj_qkv_kernel<<<gg, 256, 0, stream>>>(K, Wk, bk, kb, flag);
    proj_qkv_kernel<<<gg, 256, 0, stream>>>(V, Wv, bv, vb, flag);
    attn_kernel<<<dim3(SS / 64, BB * HH), 256, 0, stream>>>(qb, kb, vb, mask, ab);
    final_proj_kernel<<<gg, 256, 0, stream>>>(ab, Wo, bo, d_out, flag);
}

// Round 6
// 598.238 us; speedup vs baseline: 2.8387x; 2.8387x over previous
//
#include <hip/hip_runtime.h>
#include <hip/hip_bf16.h>
#include <math.h>

#define BB 8
#define SS 2048
#define HH 8
#define DKK 64
#define DM 512

typedef short bf16x8 __attribute__((ext_vector_type(8)));
typedef short bf16x4 __attribute__((ext_vector_type(4)));
typedef float f32x4 __attribute__((ext_vector_type(4)));
#define MFMA16(a, b, c) __builtin_amdgcn_mfma_f32_16x16x32_bf16(a, b, c, 0, 0, 0)

#if __has_builtin(__builtin_amdgcn_exp2f)
#define EXP2(x) __builtin_amdgcn_exp2f(x)
#else
#define EXP2(x) exp2f(x)
#endif

__device__ __forceinline__ unsigned short f2bf(float f) {
    __hip_bfloat16 h = __float2bfloat16(f);
    return *reinterpret_cast<unsigned short*>(&h);
}

// Convert 8 consecutive fp32 -> 8 bf16, return as uint4 for a 16B LDS store.
__device__ __forceinline__ uint4 cvt8(const float* __restrict__ src) {
    float4 a = *(const float4*)src;
    float4 b = *(const float4*)(src + 4);
    unsigned short tmp[8];
    tmp[0] = f2bf(a.x); tmp[1] = f2bf(a.y); tmp[2] = f2bf(a.z); tmp[3] = f2bf(a.w);
    tmp[4] = f2bf(b.x); tmp[5] = f2bf(b.y); tmp[6] = f2bf(b.z); tmp[7] = f2bf(b.w);
    return *(uint4*)tmp;
}

// ---------------------------------------------------------------------------
// QKV projection: out[m][n] = (sum_k X[m][k]*W[n][k] + bias[n]) * scale
// X fp32 [16384,512], W fp32 [512,512] ([n][k]); fp32->bf16 at LDS staging.
// out bf16 scattered to [B*H][S][64] (n = h*64+d).
// 128x128 tile, BK=64, 4 waves each 64x64 (4x4 of 16x16x32 mfma).
// ---------------------------------------------------------------------------
__global__ __launch_bounds__(256, 2) void proj_qkv_mfma(
    const float* __restrict__ X,
    const float* __restrict__ W,
    const float* __restrict__ bias,
    unsigned short* __restrict__ out,
    float scale)
{
    __shared__ __align__(16) unsigned short Xs[128][72];
    __shared__ __align__(16) unsigned short Ws[128][72];
    const int t = threadIdx.x;
    const int w = t >> 6, l = t & 63;
    const int l15 = l & 15, lg = l >> 4;
    const int n0 = blockIdx.x * 128, m0 = blockIdx.y * 128;
    const int mo = (w & 1) * 64, no = (w >> 1) * 64;

    f32x4 acc[4][4];
#pragma unroll
    for (int i = 0; i < 4; i++)
#pragma unroll
        for (int j = 0; j < 4; j++) acc[i][j] = (f32x4){0.f, 0.f, 0.f, 0.f};

    for (int k0 = 0; k0 < DM; k0 += 64) {
        __syncthreads();
#pragma unroll
        for (int rr = 0; rr < 4; rr++) {
            int idx = rr * 2048 + t * 8;
            int row = idx >> 6, col = idx & 63;
            *(uint4*)&Xs[row][col] = cvt8(X + (size_t)(m0 + row) * DM + k0 + col);
            *(uint4*)&Ws[row][col] = cvt8(W + (size_t)(n0 + row) * DM + k0 + col);
        }
        __syncthreads();

        bf16x8 af[4][2], bfr[4][2];
#pragma unroll
        for (int mt = 0; mt < 4; mt++) {
            af[mt][0] = *(const bf16x8*)&Xs[mo + mt * 16 + l15][lg * 8];
            af[mt][1] = *(const bf16x8*)&Xs[mo + mt * 16 + l15][32 + lg * 8];
        }
#pragma unroll
        for (int nt = 0; nt < 4; nt++) {
            bfr[nt][0] = *(const bf16x8*)&Ws[no + nt * 16 + l15][lg * 8];
            bfr[nt][1] = *(const bf16x8*)&Ws[no + nt * 16 + l15][32 + lg * 8];
        }
#pragma unroll
        for (int mt = 0; mt < 4; mt++)
#pragma unroll
            for (int nt = 0; nt < 4; nt++) {
                acc[mt][nt] = MFMA16(af[mt][0], bfr[nt][0], acc[mt][nt]);
                acc[mt][nt] = MFMA16(af[mt][1], bfr[nt][1], acc[mt][nt]);
            }
    }

    float bv[4];
#pragma unroll
    for (int nt = 0; nt < 4; nt++) bv[nt] = bias[n0 + no + nt * 16 + l15];

    const int h = (n0 + no) >> 6;
#pragma unroll
    for (int mt = 0; mt < 4; mt++)
#pragma unroll
        for (int nt = 0; nt < 4; nt++)
#pragma unroll
            for (int r = 0; r < 4; r++) {
                int m = m0 + mo + mt * 16 + lg * 4 + r;
                int d = nt * 16 + l15;
                float v = (acc[mt][nt][r] + bv[nt]) * scale;
                int bb = m >> 11, s = m & (SS - 1);
                out[(((size_t)bb * HH + h) * SS + s) * 64 + d] = f2bf(v);
            }
}

// ---------------------------------------------------------------------------
// Output projection: out[m][n] = sum_k A[m][k]*Wo[n][k] + bo[n]
// A bf16 [16384,512] (ws), Wo fp32 [512,512], out fp32 row-major (d_out).
// ---------------------------------------------------------------------------
__global__ __launch_bounds__(256, 2) void proj_out_mfma(
    const unsigned short* __restrict__ Xb,
    const float* __restrict__ W,
    const float* __restrict__ bias,
    float* __restrict__ out)
{
    __shared__ __align__(16) unsigned short Xs[128][72];
    __shared__ __align__(16) unsigned short Ws[128][72];
    const int t = threadIdx.x;
    const int w = t >> 6, l = t & 63;
    const int l15 = l & 15, lg = l >> 4;
    const int n0 = blockIdx.x * 128, m0 = blockIdx.y * 128;
    const int mo = (w & 1) * 64, no = (w >> 1) * 64;

    f32x4 acc[4][4];
#pragma unroll
    for (int i = 0; i < 4; i++)
#pragma unroll
        for (int j = 0; j < 4; j++) acc[i][j] = (f32x4){0.f, 0.f, 0.f, 0.f};

    for (int k0 = 0; k0 < DM; k0 += 64) {
        __syncthreads();
#pragma unroll
        for (int rr = 0; rr < 4; rr++) {
            int idx = rr * 2048 + t * 8;
            int row = idx >> 6, col = idx & 63;
            *(uint4*)&Xs[row][col] = *(const uint4*)(Xb + (size_t)(m0 + row) * DM + k0 + col);
            *(uint4*)&Ws[row][col] = cvt8(W + (size_t)(n0 + row) * DM + k0 + col);
        }
        __syncthreads();

        bf16x8 af[4][2], bfr[4][2];
#pragma unroll
        for (int mt = 0; mt < 4; mt++) {
            af[mt][0] = *(const bf16x8*)&Xs[mo + mt * 16 + l15][lg * 8];
            af[mt][1] = *(const bf16x8*)&Xs[mo + mt * 16 + l15][32 + lg * 8];
        }
#pragma unroll
        for (int nt = 0; nt < 4; nt++) {
            bfr[nt][0] = *(const bf16x8*)&Ws[no + nt * 16 + l15][lg * 8];
            bfr[nt][1] = *(const bf16x8*)&Ws[no + nt * 16 + l15][32 + lg * 8];
        }
#pragma unroll
        for (int mt = 0; mt < 4; mt++)
#pragma unroll
            for (int nt = 0; nt < 4; nt++) {
                acc[mt][nt] = MFMA16(af[mt][0], bfr[nt][0], acc[mt][nt]);
                acc[mt][nt] = MFMA16(af[mt][1], bfr[nt][1], acc[mt][nt]);
            }
    }

    float bv[4];
#pragma unroll
    for (int nt = 0; nt < 4; nt++) bv[nt] = bias[n0 + no + nt * 16 + l15];

#pragma unroll
    for (int mt = 0; mt < 4; mt++)
#pragma unroll
        for (int nt = 0; nt < 4; nt++)
#pragma unroll
            for (int r = 0; r < 4; r++) {
                int m = m0 + mo + mt * 16 + lg * 4 + r;
                int n = n0 + no + nt * 16 + l15;
                out[(size_t)m * DM + n] = acc[mt][nt][r] + bv[nt];
            }
}

// ---------------------------------------------------------------------------
// Flash attention, bf16 MFMA. Block = (qblock of 256 rows) x (b,h).
// 4 waves; wave w owns q rows [w*64, w*64+64). kv tiles of 64.
// S^T = K·Q^T (C-layout packs 4 consecutive kv per lane -> packed 8B P-store).
// Softmax in exp2 domain (log2e folded into q). Mask int4-loaded directly;
// masked -> -1e38 (reference masked_fill semantics).
// ---------------------------------------------------------------------------
__global__ __launch_bounds__(256, 2) void attn_kernel(
    const unsigned short* __restrict__ qw, const unsigned short* __restrict__ kw,
    const unsigned short* __restrict__ vw,
    const int* __restrict__ mask,
    unsigned short* __restrict__ ao)   // [B,S,512] bf16
{
    __shared__ __align__(16) unsigned short Ks[64][72];   // [kv][d]
    __shared__ __align__(16) unsigned short Vt[64][72];   // [d][kv]
    __shared__ __align__(16) unsigned short Pw[4][64][72];// per-wave [q][kv]
    const int t = threadIdx.x;
    const int w = t >> 6, l = t & 63;
    const int l15 = l & 15, lg = l >> 4;
    const int q0 = blockIdx.x * 256;
    const int bh = blockIdx.y;
    const int b = bh >> 3, h = bh & 7;
    const int q0w = q0 + w * 64;
    const unsigned short* qb = qw + (size_t)bh * SS * DKK;
    const unsigned short* kb = kw + (size_t)bh * SS * DKK;
    const unsigned short* vb = vw + (size_t)bh * SS * DKK;

    // Q fragments (B-operand): Qf[qt][dh] = Q[q0w+qt*16+l15][dh*32+lg*8 ..+8]
    bf16x8 Qf[4][2];
#pragma unroll
    for (int qt = 0; qt < 4; qt++)
#pragma unroll
        for (int dh = 0; dh < 2; dh++)
            Qf[qt][dh] = *(const bf16x8*)(qb + (size_t)(q0w + qt * 16 + l15) * DKK + dh * 32 + lg * 8);

    f32x4 O[4][4];   // [qt][dt]: row q = qt*16+lg*4+r, col d = dt*16+l15
#pragma unroll
    for (int i = 0; i < 4; i++)
#pragma unroll
        for (int j = 0; j < 4; j++) O[i][j] = (f32x4){0.f, 0.f, 0.f, 0.f};
    float m_i[4], l_i[4];
#pragma unroll
    for (int i = 0; i < 4; i++) { m_i[i] = -INFINITY; l_i[i] = 0.f; }

    for (int kv0 = 0; kv0 < SS; kv0 += 64) {
        __syncthreads();   // all waves done with Ks/Vt/Pw of previous tile
        // ---- stage K tile + transposed V tile ----
#pragma unroll
        for (int r = 0; r < 2; r++) {
            int idx = r * 2048 + t * 8;
            int row = idx >> 6, col = idx & 63;
            *(uint4*)&Ks[row][col] = *(const uint4*)(kb + (size_t)(kv0 + row) * DKK + col);
            unsigned short vt[8];
            *(uint4*)vt = *(const uint4*)(vb + (size_t)(kv0 + row) * DKK + col);
#pragma unroll
            for (int j = 0; j < 8; j++) Vt[col + j][row] = vt[j];
        }
        __syncthreads();

        // ---- S^T = K·Q^T : S[kvt][qt], row kv = kvt*16+lg*4+r, col q = qt*16+l15
        f32x4 S[4][4];
#pragma unroll
        for (int kvt = 0; kvt < 4; kvt++) {
            bf16x8 ak0 = *(const bf16x8*)&Ks[kvt * 16 + l15][lg * 8];
            bf16x8 ak1 = *(const bf16x8*)&Ks[kvt * 16 + l15][32 + lg * 8];
#pragma unroll
            for (int qt = 0; qt < 4; qt++) {
                f32x4 z = (f32x4){0.f, 0.f, 0.f, 0.f};
                z = MFMA16(ak0, Qf[qt][0], z);
                z = MFMA16(ak1, Qf[qt][1], z);
                S[kvt][qt] = z;
            }
        }

        // ---- mask: direct int4 loads; components = the 4 kv regs ----
#pragma unroll
        for (int qt = 0; qt < 4; qt++) {
            const int* mrow = mask + (size_t)(q0w + qt * 16 + l15) * SS + kv0 + lg * 4;
#pragma unroll
            for (int kvt = 0; kvt < 4; kvt++) {
                int4 mm = *(const int4*)(mrow + kvt * 16);
                if (mm.x == 0) S[kvt][qt][0] = -1e38f;
                if (mm.y == 0) S[kvt][qt][1] = -1e38f;
                if (mm.z == 0) S[kvt][qt][2] = -1e38f;
                if (mm.w == 0) S[kvt][qt][3] = -1e38f;
            }
        }

        // ---- online softmax (exp2 domain) ----
        float mnew[4], alpha[4];
#pragma unroll
        for (int qt = 0; qt < 4; qt++) {
            float mt = S[0][qt][0];
#pragma unroll
            for (int kvt = 0; kvt < 4; kvt++)
#pragma unroll
                for (int r = 0; r < 4; r++) mt = fmaxf(mt, S[kvt][qt][r]);
            mt = fmaxf(mt, __shfl_xor(mt, 16));
            mt = fmaxf(mt, __shfl_xor(mt, 32));
            float mn = fmaxf(m_i[qt], mt);
            alpha[qt] = EXP2(m_i[qt] - mn);
            m_i[qt] = mn;
            mnew[qt] = mn;
        }
#pragma unroll
        for (int qt = 0; qt < 4; qt++) {
            float ls = 0.f;
#pragma unroll
            for (int kvt = 0; kvt < 4; kvt++) {
                float p0 = EXP2(S[kvt][qt][0] - mnew[qt]);
                float p1 = EXP2(S[kvt][qt][1] - mnew[qt]);
                float p2 = EXP2(S[kvt][qt][2] - mnew[qt]);
                float p3 = EXP2(S[kvt][qt][3] - mnew[qt]);
                ls += (p0 + p1) + (p2 + p3);
                bf16x4 pk;
                pk[0] = (short)f2bf(p0); pk[1] = (short)f2bf(p1);
                pk[2] = (short)f2bf(p2); pk[3] = (short)f2bf(p3);
                *(bf16x4*)&Pw[w][qt * 16 + l15][kvt * 16 + lg * 4] = pk;
            }
            ls += __shfl_xor(ls, 16);
            ls += __shfl_xor(ls, 32);
            l_i[qt] = l_i[qt] * alpha[qt] + ls;
        }

        // order Pw stores before the cross-lane PV fragment reads
        __syncthreads();

        // ---- rescale O by alpha (broadcast from q-col lanes to q-row regs)
#pragma unroll
        for (int qt = 0; qt < 4; qt++)
#pragma unroll
            for (int r = 0; r < 4; r++) {
                float a = __shfl(alpha[qt], lg * 4 + r);
#pragma unroll
                for (int dt = 0; dt < 4; dt++) O[qt][dt][r] *= a;
            }

        // ---- O += P·V ----
        bf16x8 bv2[4][2];
#pragma unroll
        for (int dt = 0; dt < 4; dt++) {
            bv2[dt][0] = *(const bf16x8*)&Vt[dt * 16 + l15][lg * 8];
            bv2[dt][1] = *(const bf16x8*)&Vt[dt * 16 + l15][32 + lg * 8];
        }
#pragma unroll
        for (int qt = 0; qt < 4; qt++) {
            bf16x8 ap0 = *(const bf16x8*)&Pw[w][qt * 16 + l15][lg * 8];
            bf16x8 ap1 = *(const bf16x8*)&Pw[w][qt * 16 + l15][32 + lg * 8];
#pragma unroll
            for (int dt = 0; dt < 4; dt++) {
                O[qt][dt] = MFMA16(ap0, bv2[dt][0], O[qt][dt]);
                O[qt][dt] = MFMA16(ap1, bv2[dt][1], O[qt][dt]);
            }
        }
    }

    // ---- epilogue: normalize by l, store bf16 to [b][s][h*64+d] ----
#pragma unroll
    for (int qt = 0; qt < 4; qt++) {
        float li = 1.f / l_i[qt];
#pragma unroll
        for (int r = 0; r < 4; r++) {
            float lv = __shfl(li, lg * 4 + r);
            int q = q0w + qt * 16 + lg * 4 + r;
            size_t base = ((size_t)b * SS + q) * DM + h * 64;
#pragma unroll
            for (int dt = 0; dt < 4; dt++)
                ao[base + dt * 16 + l15] = f2bf(O[qt][dt][r] * lv);
        }
    }
}

extern "C" void kernel_launch(void* const* d_in, const int* in_sizes, int n_in,
                              void* d_out, int out_size, void* d_ws, size_t ws_size,
                              hipStream_t stream) {
    // All float tensors are fp32 (proven: round-2's runtime-detect fp32 path
    // passed; hard-coded-bf16 rounds 1/3/4/5 NaN'd). mask is int32.
    const float* Q    = (const float*)d_in[0];
    const float* K    = (const float*)d_in[1];
    const float* V    = (const float*)d_in[2];
    const int*   mask = (const int*)d_in[3];
    const float* Wq   = (const float*)d_in[4];
    const float* bq   = (const float*)d_in[5];
    const float* Wk   = (const float*)d_in[6];
    const float* bk   = (const float*)d_in[7];
    const float* Wv   = (const float*)d_in[8];
    const float* bv   = (const float*)d_in[9];
    const float* Wo   = (const float*)d_in[10];
    const float* bo   = (const float*)d_in[11];

    // ws: [qb 16 MB][kb 16 MB][vb 16 MB][ab 16 MB] = 64 MB (proven-safe)
    const size_t SEG = (size_t)BB * HH * SS * DKK;  // 8,388,608 bf16 elems
    unsigned short* qb = (unsigned short*)d_ws;
    unsigned short* kb = qb + SEG;
    unsigned short* vb = kb + SEG;
    unsigned short* ab = vb + SEG;

    const float qscale = 0.125f * 1.44269504088896340736f;  // 1/sqrt(dk) * log2(e)

    dim3 gp(DM / 128, (BB * SS) / 128);  // (4, 128)
    proj_qkv_mfma<<<gp, 256, 0, stream>>>(Q, Wq, bq, qb, qscale);
    proj_qkv_mfma<<<gp, 256, 0, stream>>>(K, Wk, bk, kb, 1.0f);
    proj_qkv_mfma<<<gp, 256, 0, stream>>>(V, Wv, bv, vb, 1.0f);

    attn_kernel<<<dim3(SS / 256, BB * HH), 256, 0, stream>>>(qb, kb, vb, mask, ab);

    proj_out_mfma<<<gp, 256, 0, stream>>>(ab, Wo, bo, (float*)d_out);
}